// Round 1
// 596.325 us; speedup vs baseline: 1.0016x; 1.0016x over previous
//
#include <hip/hip_runtime.h>
#include <hip/hip_bf16.h>

// Problem constants
#define BB 32
#define TT 1500
#define TP 1536      // T padded to 12*128 for GEMM tiles
#define EE 512
#define HH 4
#define AA 512
#define NN 2048      // H*A
#define CC 10
#define KCONV 201
#define KAUG 576     // 512 enc + 40 conv + 24 zero pad (18 k-steps of 32)

typedef __attribute__((ext_vector_type(8))) __bf16 bf16x8;
typedef __attribute__((ext_vector_type(4))) float f32x4;

// ---------- helpers ----------
__device__ __forceinline__ unsigned short f2bf(float x) {
    unsigned int u = __float_as_uint(x);
    u = (u + 0x7fffu + ((u >> 16) & 1u)) >> 16;   // RNE, inputs always finite
    return (unsigned short)u;
}
__device__ __forceinline__ float bf2f(unsigned short u) {
    return __uint_as_float(((unsigned int)u) << 16);
}
__device__ __forceinline__ void glds16(const void* g, void* l) {
    __builtin_amdgcn_global_load_lds(
        (const __attribute__((address_space(1))) unsigned int*)g,
        (__attribute__((address_space(3))) unsigned int*)l, 16, 0, 0);
}
// tanh(x) = 1 - 2/(e^{2x}+1); v_exp_f32+v_rcp_f32, ~5 VALU insts.
__device__ __forceinline__ float tanh_fast(float x) {
    float e = __expf(x * 2.0f);
    return fmaf(-2.0f, __builtin_amdgcn_rcpf(e + 1.0f), 1.0f);
}

// Fused prep kernel: block-range dispatch of 5 independent phases.
#define PREP_DEC0   0
#define PREP_CONV0  1024
#define PREP_WT0    8704
#define PREP_PAD0   13312
#define PREP_ENC0   20404
#define PREP_TOTAL  44404

__global__ __launch_bounds__(256) void k_prep(
    const float* __restrict__ enc, const int* __restrict__ xl,
    const float* __restrict__ dec_out, const float* __restrict__ aw_step,
    const float* __restrict__ w_enc, const float* __restrict__ b_enc,
    const float* __restrict__ w_dec, const float* __restrict__ w_conv,
    const float* __restrict__ conv_k,
    unsigned short* __restrict__ Whi, unsigned short* __restrict__ Wlo,
    unsigned short* __restrict__ Ahi, unsigned short* __restrict__ Alo,
    float* __restrict__ dec_a) {
    __shared__ float sbuf[456 + KCONV];
    const int bid = blockIdx.x;
    const int tid = threadIdx.x;

    if (bid < PREP_CONV0) {
        // ---- dec: dec_a[b][n] = b_enc[n] + sum_d dec[b][d]*w_dec[h][d][a] ----
        const int b  = bid >> 5;
        const int n0 = (bid & 31) * 64;
        const int n  = n0 + (tid & 63);
        const int dg = tid >> 6;                   // 0..3, 128 d each
        const int h  = n >> 9, a = n & 511;
        const float* dp = dec_out + (size_t)b * 512 + dg * 128;
        const float* wp = w_dec + ((size_t)h * 512 + dg * 128) * 512 + a;
        float acc = 0.f;
#pragma unroll 8
        for (int d = 0; d < 128; ++d) acc += dp[d] * wp[(size_t)d * 512];
        sbuf[tid] = acc;
        __syncthreads();
        if (tid < 64) {
            float tot = sbuf[tid] + sbuf[tid + 64] + sbuf[tid + 128] + sbuf[tid + 192];
            dec_a[(size_t)b * NN + n0 + tid] = b_enc[n0 + tid] + tot;
        }
    } else if (bid < PREP_WT0) {
        // ---- conv: grouped 1D conv over aw_step -> A cols [512,552) ----
        int r = bid - PREP_CONV0;                  // 7680 = 6*40*32
        const int tch = r % 6;
        const int hc  = (r / 6) % 40;
        const int b   = r / 240;
        const int h   = hc / 10;
        const int t0  = tch * 256;
        float* sAw = sbuf;
        float* sK  = sbuf + 456;
        for (int i = tid; i < 456; i += 256) {
            int ts = t0 - 100 + i;
            sAw[i] = (ts >= 0 && ts < TT) ? aw_step[((size_t)b * TT + ts) * HH + h] : 0.f;
        }
        if (tid < KCONV) sK[tid] = conv_k[(size_t)hc * KCONV + tid];
        __syncthreads();
        int t = t0 + tid;
        if (t < TT) {
            float acc = 0.f;
            for (int k = 0; k < KCONV; ++k) acc += sAw[tid + k] * sK[k];
            size_t o = ((size_t)b * TP + t) * KAUG + 512 + hc;
            unsigned short hi = f2bf(acc);
            Ahi[o] = hi; Alo[o] = f2bf(acc - bf2f(hi));
        }
    } else if (bid < PREP_PAD0) {
        // ---- wt: W planes [N=2048][KAUG], hi/lo ----
        int idx = (bid - PREP_WT0) * 256 + tid;    // 1,179,648
        int n = idx / KAUG, k = idx % KAUG;
        int h = n >> 9, a = n & 511;
        float val = 0.f;
        if (k < 512) {
            val = w_enc[((size_t)h * 512 + k) * 512 + a];
        } else if (k < 552) {
            int j = k - 512; int h2 = j / 10, c = j % 10;
            if (h2 == h) val = w_conv[((size_t)h * 10 + c) * 512 + a];
        }
        unsigned short hi = f2bf(val);
        Whi[idx] = hi;
        Wlo[idx] = f2bf(val - bf2f(hi));
    } else if (bid < PREP_ENC0) {
        // ---- pad: zero rows >=1500 (all cols) + cols [552,576) (rows <1500) ----
        int idx = (bid - PREP_PAD0) * 256 + tid;
        const int tot1 = BB * 36 * KAUG;           // 663552
        const int tot2 = BB * TT * 24;             // 1152000
        size_t o;
        if (idx < tot1) {
            int b = idx / (36 * KAUG); int r2 = idx % (36 * KAUG);
            int t = 1500 + r2 / KAUG;  int k = r2 % KAUG;
            o = ((size_t)b * TP + t) * KAUG + k;
        } else if (idx < tot1 + tot2) {
            int j = idx - tot1;
            int b = j / (TT * 24); int r2 = j % (TT * 24);
            int t = r2 / 24;       int k = 552 + r2 % 24;
            o = ((size_t)b * TP + t) * KAUG + k;
        } else return;
        Ahi[o] = 0; Alo[o] = 0;
    } else {
        // ---- enc: f32 -> A planes cols [0,512); Alo only for 3-product tiles ----
        long idx = (long)(bid - PREP_ENC0) * 256 + tid;   // 6,144,000 float4s
        if (idx >= 6144000L) return;
        long f = idx * 4;
        int b = (int)(f / 768000);
        int r2 = (int)(f % 768000);
        int t = r2 >> 9, e = r2 & 511;
        float4 vv = *reinterpret_cast<const float4*>(enc + f);
        ushort4 h4;
        h4.x = f2bf(vv.x); h4.y = f2bf(vv.y); h4.z = f2bf(vv.z); h4.w = f2bf(vv.w);
        size_t o = ((size_t)b * TP + t) * KAUG + e;
        *reinterpret_cast<ushort4*>(Ahi + o) = h4;
        if (((t & ~127) + 128) > xl[b]) {          // tile containing t runs 3-product
            ushort4 l4;
            l4.x = f2bf(vv.x - bf2f(h4.x));
            l4.y = f2bf(vv.y - bf2f(h4.y));
            l4.z = f2bf(vv.z - bf2f(h4.z));
            l4.w = f2bf(vv.w - bf2f(h4.w));
            *reinterpret_cast<ushort4*>(Alo + o) = l4;
        }
    }
}

// ---------- GEMM kernels: double-buffered LDS, prefetch-next-tile, XOR-swizzled ----------
// Structure (T3 minimum-2-phase): per K-step issue next tile's global_load_lds into
// buf^1 FIRST, then ds_read+MFMA current buf, then ONE vmcnt(0) (issue-to-wait distance
// = whole compute phase) + raw s_barrier. __syncthreads is NOT used in the loop (it
// would drain the prefetch).
// LDS swizzle (both-sides-or-neither, rule #21): global_load_lds writes linearly, so
// the 16B chunk permutation c' = c ^ ((row>>1)&3) is applied on the GLOBAL source
// address (ko) and on the ds_read offset (fo). 16-lane read phases then touch 8
// distinct bank-quads (2 lanes each) -> conflict-free.
// XCD swizzle (bijective, grid%8==0): consecutive cids on one XCD sweep all 16 ntiles
// of one (mtile,b) -> A-tile stays in that XCD's L2.

// Epilogue shared by both kernels.
__device__ __forceinline__ void gemm_epilogue(
    f32x4 acc[4][4], const float* __restrict__ dec_a, const float* __restrict__ vvec,
    float* __restrict__ energy, int b, int m0, int n0, int ntile,
    int lane, int wm, int wn) {
    const int h = ntile >> 2;            // 128-wide tile lies inside one head
    const int kg = lane >> 4;
    float dv[4], vv[4];
#pragma unroll
    for (int j = 0; j < 4; j++) {
        int ng = n0 + wn * 64 + j * 16 + (lane & 15);
        dv[j] = dec_a[(size_t)b * NN + ng];
        vv[j] = vvec[ng];
    }
#pragma unroll
    for (int i = 0; i < 4; i++) {
        float part[4] = {0.f, 0.f, 0.f, 0.f};
#pragma unroll
        for (int j = 0; j < 4; j++)
#pragma unroll
            for (int r = 0; r < 4; r++)
                part[r] += tanh_fast(acc[i][j][r] + dv[j]) * vv[j];
#pragma unroll
        for (int r = 0; r < 4; r++) {
            float s = part[r];
            s += __shfl_xor(s, 1, 64);
            s += __shfl_xor(s, 2, 64);
            s += __shfl_xor(s, 4, 64);
            s += __shfl_xor(s, 8, 64);
            if ((lane & 15) == 0) {
                int t = m0 + wm * 64 + i * 16 + kg * 4 + r;
                if (t < TT)
                    atomicAdd(&energy[((size_t)b * HH + h) * TP + t], s);
            }
        }
    }
}

// 1-product kernel: fully-valid tiles only. 32 KB LDS (2 planes, double-buffered).
__global__ __launch_bounds__(256) void k_gemm1(
    const unsigned short* __restrict__ Ahi, const unsigned short* __restrict__ Whi,
    const float* __restrict__ dec_a, const float* __restrict__ vvec,
    const int* __restrict__ xl, float* __restrict__ energy) {
    __shared__ unsigned short lsA[2][128 * 32];
    __shared__ unsigned short lsB[2][128 * 32];
    const int bid = (int)blockIdx.x + 16 * ((int)blockIdx.y + 12 * (int)blockIdx.z);
    const int cid = (bid & 7) * 768 + (bid >> 3);       // 6144 % 8 == 0: bijective
    const int ntile = cid & 15;
    const int mtile = (cid >> 4) % 12;
    const int b = cid / 192;
    const int m0 = mtile * 128, n0 = ntile * 128;
    if (m0 + 128 > xl[b]) return;                        // edge tile: k_gemm3's job

    const int tid = threadIdx.x;
    const int lane = tid & 63, wave = tid >> 6;
    const int wm = wave >> 1, wn = wave & 1;

    f32x4 acc[4][4];
#pragma unroll
    for (int i = 0; i < 4; i++)
#pragma unroll
        for (int j = 0; j < 4; j++) acc[i][j] = (f32x4){0.f, 0.f, 0.f, 0.f};

    const int row = tid >> 2;
    const int ko  = ((tid & 3) ^ ((tid >> 3) & 3)) * 8;  // pre-swizzled global source
    const size_t abase = ((size_t)b * TP + m0 + row) * KAUG + ko;
    const size_t bbase = ((size_t)n0 + row) * KAUG + ko;
    const int l1 = tid * 8;                              // linear LDS dest (required)
    const int l2 = l1 + 64 * 32;
    const int ar = wm * 64, br = wn * 64;
    const int fo = (lane & 15) * 32 + (((lane >> 4) ^ ((lane >> 1) & 3)) * 8);

    auto stage = [&](int buf, int k0) {
        glds16(Ahi + abase + k0,                     &lsA[buf][l1]);
        glds16(Ahi + abase + k0 + (size_t)64 * KAUG, &lsA[buf][l2]);
        glds16(Whi + bbase + k0,                     &lsB[buf][l1]);
        glds16(Whi + bbase + k0 + (size_t)64 * KAUG, &lsB[buf][l2]);
    };
    auto compute = [&](int buf) {
        bf16x8 ah[4], bh[4];
#pragma unroll
        for (int i = 0; i < 4; i++) {
            ah[i] = *(const bf16x8*)&lsA[buf][(ar + i * 16) * 32 + fo];
            bh[i] = *(const bf16x8*)&lsB[buf][(br + i * 16) * 32 + fo];
        }
        __builtin_amdgcn_s_setprio(1);
#pragma unroll
        for (int i = 0; i < 4; i++)
#pragma unroll
            for (int j = 0; j < 4; j++)
                acc[i][j] = __builtin_amdgcn_mfma_f32_16x16x32_bf16(ah[i], bh[j], acc[i][j], 0, 0, 0);
        __builtin_amdgcn_s_setprio(0);
    };

    stage(0, 0);
    asm volatile("s_waitcnt vmcnt(0)" ::: "memory");
    __builtin_amdgcn_s_barrier();
    __builtin_amdgcn_sched_barrier(0);

    int cur = 0;
    for (int ks = 0; ks < 17; ++ks) {
        stage(cur ^ 1, (ks + 1) * 32);     // prefetch next tile (hidden under MFMA)
        compute(cur);
        __builtin_amdgcn_sched_barrier(0); // pin MFMAs (and their lgkm waits) above
        asm volatile("s_waitcnt vmcnt(0)" ::: "memory");  // only the 4 prefetch loads
        __builtin_amdgcn_s_barrier();
        __builtin_amdgcn_sched_barrier(0); // no ds_read hoists above the barrier
        cur ^= 1;
    }
    compute(cur);

    gemm_epilogue(acc, dec_a, vvec, energy, b, m0, n0, ntile, lane, wm, wn);
}

// 3-product kernel: tiles containing padded rows (t >= xlen), where the reference's
// *(-1024) mask amplifies energy error x1024. 64 KB LDS (4 planes, double-buffered).
// Only mtiles 5..11 can be edge tiles (xlen >= 750).
__global__ __launch_bounds__(256) void k_gemm3(
    const unsigned short* __restrict__ Ahi, const unsigned short* __restrict__ Alo,
    const unsigned short* __restrict__ Whi, const unsigned short* __restrict__ Wlo,
    const float* __restrict__ dec_a, const float* __restrict__ vvec,
    const int* __restrict__ xl, float* __restrict__ energy) {
    __shared__ unsigned short lsAh[2][128 * 32], lsAl[2][128 * 32];
    __shared__ unsigned short lsBh[2][128 * 32], lsBl[2][128 * 32];
    const int bid = (int)blockIdx.x + 16 * ((int)blockIdx.y + 7 * (int)blockIdx.z);
    const int cid = (bid & 7) * 448 + (bid >> 3);       // 3584 % 8 == 0: bijective
    const int ntile = cid & 15;
    const int mtile = 5 + ((cid >> 4) % 7);
    const int b = cid / 112;
    const int m0 = mtile * 128, n0 = ntile * 128;
    if (m0 + 128 <= xl[b]) return;                       // fully valid: k_gemm1's job

    const int tid = threadIdx.x;
    const int lane = tid & 63, wave = tid >> 6;
    const int wm = wave >> 1, wn = wave & 1;

    f32x4 acc[4][4];
#pragma unroll
    for (int i = 0; i < 4; i++)
#pragma unroll
        for (int j = 0; j < 4; j++) acc[i][j] = (f32x4){0.f, 0.f, 0.f, 0.f};

    const int row = tid >> 2;
    const int ko  = ((tid & 3) ^ ((tid >> 3) & 3)) * 8;
    const size_t abase = ((size_t)b * TP + m0 + row) * KAUG + ko;
    const size_t bbase = ((size_t)n0 + row) * KAUG + ko;
    const int l1 = tid * 8;
    const int l2 = l1 + 64 * 32;
    const int ar = wm * 64, br = wn * 64;
    const int fo = (lane & 15) * 32 + (((lane >> 4) ^ ((lane >> 1) & 3)) * 8);

    auto stage = [&](int buf, int k0) {
        glds16(Ahi + abase + k0,                     &lsAh[buf][l1]);
        glds16(Ahi + abase + k0 + (size_t)64 * KAUG, &lsAh[buf][l2]);
        glds16(Alo + abase + k0,                     &lsAl[buf][l1]);
        glds16(Alo + abase + k0 + (size_t)64 * KAUG, &lsAl[buf][l2]);
        glds16(Whi + bbase + k0,                     &lsBh[buf][l1]);
        glds16(Whi + bbase + k0 + (size_t)64 * KAUG, &lsBh[buf][l2]);
        glds16(Wlo + bbase + k0,                     &lsBl[buf][l1]);
        glds16(Wlo + bbase + k0 + (size_t)64 * KAUG, &lsBl[buf][l2]);
    };
    auto compute = [&](int buf) {
        bf16x8 ah[4], al[4], bh[4], bl[4];
#pragma unroll
        for (int i = 0; i < 4; i++) {
            ah[i] = *(const bf16x8*)&lsAh[buf][(ar + i * 16) * 32 + fo];
            al[i] = *(const bf16x8*)&lsAl[buf][(ar + i * 16) * 32 + fo];
            bh[i] = *(const bf16x8*)&lsBh[buf][(br + i * 16) * 32 + fo];
            bl[i] = *(const bf16x8*)&lsBl[buf][(br + i * 16) * 32 + fo];
        }
        __builtin_amdgcn_s_setprio(1);
#pragma unroll
        for (int i = 0; i < 4; i++)
#pragma unroll
            for (int j = 0; j < 4; j++) {
                acc[i][j] = __builtin_amdgcn_mfma_f32_16x16x32_bf16(ah[i], bh[j], acc[i][j], 0, 0, 0);
                acc[i][j] = __builtin_amdgcn_mfma_f32_16x16x32_bf16(ah[i], bl[j], acc[i][j], 0, 0, 0);
                acc[i][j] = __builtin_amdgcn_mfma_f32_16x16x32_bf16(al[i], bh[j], acc[i][j], 0, 0, 0);
            }
        __builtin_amdgcn_s_setprio(0);
    };

    stage(0, 0);
    asm volatile("s_waitcnt vmcnt(0)" ::: "memory");
    __builtin_amdgcn_s_barrier();
    __builtin_amdgcn_sched_barrier(0);

    int cur = 0;
    for (int ks = 0; ks < 17; ++ks) {
        stage(cur ^ 1, (ks + 1) * 32);
        compute(cur);
        __builtin_amdgcn_sched_barrier(0);
        asm volatile("s_waitcnt vmcnt(0)" ::: "memory");
        __builtin_amdgcn_s_barrier();
        __builtin_amdgcn_sched_barrier(0);
        cur ^= 1;
    }
    compute(cur);

    gemm_epilogue(acc, dec_a, vvec, energy, b, m0, n0, ntile, lane, wm, wn);
}

// ---------- masked softmax over time (replicates energy * (+1 / -1024) mask) ----------
__global__ __launch_bounds__(512) void k_softmax(const float* __restrict__ energy,
                                                 const int* __restrict__ x_lens,
                                                 float* __restrict__ aw) {
    const int b = blockIdx.x >> 2, h = blockIdx.x & 3;
    const int tid = threadIdx.x;
    __shared__ float sE[TT];
    __shared__ float red[512];
    const int xlen = x_lens[b];
    float lmax = -3.4e38f;
    for (int t = tid; t < TT; t += 512) {
        float e = energy[((size_t)b * HH + h) * TP + t];
        float m = (t < xlen) ? e : e * -1024.0f;
        sE[t] = m;
        lmax = fmaxf(lmax, m);
    }
    red[tid] = lmax; __syncthreads();
    for (int s = 256; s > 0; s >>= 1) { if (tid < s) red[tid] = fmaxf(red[tid], red[tid + s]); __syncthreads(); }
    float mx = red[0]; __syncthreads();
    float lsum = 0.f;
    for (int t = tid; t < TT; t += 512) {
        float ex = expf(sE[t] - mx);
        sE[t] = ex; lsum += ex;
    }
    red[tid] = lsum; __syncthreads();
    for (int s = 256; s > 0; s >>= 1) { if (tid < s) red[tid] += red[tid + s]; __syncthreads(); }
    float sum = red[0];
    for (int t = tid; t < TT; t += 512)
        aw[((size_t)b * TT + t) * HH + h] = sE[t] / sum;
}

// ---------- ctx_h[b][h][e] = sum_t aw[b][t][h] * enc[b][t][e] ----------
__global__ __launch_bounds__(512) void k_ctx(const float* __restrict__ enc,
                                             const float* __restrict__ aw,
                                             float* __restrict__ ctx_h) {
    const int chunk = blockIdx.x, b = blockIdx.y;
    const int t0 = chunk * 128;
    const int nt = (TT - t0 < 128) ? (TT - t0) : 128;
    __shared__ float sA[128 * 4];
    const int tid = threadIdx.x;
    for (int i = tid; i < nt * 4; i += 512)
        sA[i] = aw[((size_t)b * TT + t0) * HH + i];
    __syncthreads();
    float a0 = 0.f, a1 = 0.f, a2 = 0.f, a3 = 0.f;
    const float* ep = enc + ((size_t)b * TT + t0) * EE + tid;
    if (nt == 128) {
#pragma unroll 8
        for (int tt = 0; tt < 128; ++tt) {
            float ev = ep[(size_t)tt * EE];
            a0 += sA[tt * 4 + 0] * ev; a1 += sA[tt * 4 + 1] * ev;
            a2 += sA[tt * 4 + 2] * ev; a3 += sA[tt * 4 + 3] * ev;
        }
    } else {
        for (int tt = 0; tt < nt; ++tt) {
            float ev = ep[(size_t)tt * EE];
            a0 += sA[tt * 4 + 0] * ev; a1 += sA[tt * 4 + 1] * ev;
            a2 += sA[tt * 4 + 2] * ev; a3 += sA[tt * 4 + 3] * ev;
        }
    }
    atomicAdd(&ctx_h[((size_t)b * HH + 0) * EE + tid], a0);
    atomicAdd(&ctx_h[((size_t)b * HH + 1) * EE + tid], a1);
    atomicAdd(&ctx_h[((size_t)b * HH + 2) * EE + tid], a2);
    atomicAdd(&ctx_h[((size_t)b * HH + 3) * EE + tid], a3);
}

// ---------- ctx = ctx_h @ w_mha + b_mha ----------
__global__ __launch_bounds__(256) void k_mha(const float* __restrict__ ctx_h,
                                             const float* __restrict__ w_mha,
                                             const float* __restrict__ b_mha,
                                             float* __restrict__ out) {
    __shared__ float sred[256];
    const int tid = threadIdx.x;
    const int b  = blockIdx.x >> 2;
    const int eo = ((blockIdx.x & 3) << 7) + (tid & 127);
    const int kg = tid >> 7;                   // 0..1, 1024 k each
    const float* c = ctx_h + (size_t)b * NN + kg * 1024;
    const float* w = w_mha + ((size_t)kg * 1024) * EE + eo;
    float acc = 0.f;
#pragma unroll 8
    for (int k = 0; k < 1024; ++k) acc += c[k] * w[(size_t)k * EE];
    sred[tid] = acc;
    __syncthreads();
    if (tid < 128)
        out[(size_t)b * EE + eo] = b_mha[eo] + sred[tid] + sred[tid + 128];
}

extern "C" void kernel_launch(void* const* d_in, const int* in_sizes, int n_in,
                              void* d_out, int out_size, void* d_ws, size_t ws_size,
                              hipStream_t stream) {
    (void)in_sizes; (void)n_in; (void)out_size;
    const float* enc    = (const float*)d_in[0];
    const int*   xlen   = (const int*)d_in[1];
    const float* dec    = (const float*)d_in[2];
    const float* aw_in  = (const float*)d_in[3];
    const float* w_enc  = (const float*)d_in[4];
    const float* b_enc  = (const float*)d_in[5];
    const float* w_dec  = (const float*)d_in[6];
    const float* w_conv = (const float*)d_in[7];
    const float* convk  = (const float*)d_in[8];
    const float* v      = (const float*)d_in[9];
    const float* w_mha  = (const float*)d_in[10];
    const float* b_mha  = (const float*)d_in[11];
    float* out = (float*)d_out;

    // ws layout (needs ~119.3 MB)
    char* ws = (char*)d_ws;
    unsigned short* Whi = (unsigned short*)ws;                          // 2,359,296 B
    unsigned short* Wlo = Whi + (size_t)NN * KAUG;                      // 2,359,296 B
    unsigned short* Ahi = (unsigned short*)(ws + 4718592);              // 56,623,104 B
    unsigned short* Alo = Ahi + (size_t)BB * TP * KAUG;                 // 56,623,104 B
    float* dec_a  = (float*)(ws + 117964800);                           //   262,144 B
    float* energy = (float*)(ws + 118226944);                           //   786,432 B
    float* ctx_h  = (float*)(ws + 119013376);                           //   262,144 B
    (void)ws_size;

    hipMemsetAsync(energy, 0, 786432 + 262144, stream);  // energy + ctx_h (contiguous)

    k_prep<<<dim3(PREP_TOTAL), 256, 0, stream>>>(enc, xlen, dec, aw_in, w_enc, b_enc,
                                                 w_dec, w_conv, convk,
                                                 Whi, Wlo, Ahi, Alo, dec_a);
    k_gemm1<<<dim3(16, 12, BB), 256, 0, stream>>>(Ahi, Whi, dec_a, v, xlen, energy);
    k_gemm3<<<dim3(16, 7, BB), 256, 0, stream>>>(Ahi, Alo, Whi, Wlo, dec_a, v, xlen, energy);
    k_softmax<<<dim3(BB * HH), 512, 0, stream>>>(energy, xlen, out + 16384);
    k_ctx <<<dim3(12, BB), 512, 0, stream>>>(enc, out + 16384, ctx_h);
    k_mha <<<dim3(128), 256, 0, stream>>>(ctx_h, w_mha, b_mha, out);
}

// Round 2
// 595.236 us; speedup vs baseline: 1.0034x; 1.0018x over previous
//
#include <hip/hip_runtime.h>
#include <hip/hip_bf16.h>

// Problem constants
#define BB 32
#define TT 1500
#define TP 1536      // T padded to 12*128 for GEMM tiles
#define EE 512
#define HH 4
#define AA 512
#define NN 2048      // H*A
#define CC 10
#define KCONV 201
#define KAUG 576     // 512 enc + 40 conv + 24 zero pad (18 k-steps of 32)

typedef __attribute__((ext_vector_type(8))) __bf16 bf16x8;
typedef __attribute__((ext_vector_type(4))) float f32x4;

// ---------- helpers ----------
__device__ __forceinline__ unsigned short f2bf(float x) {
    unsigned int u = __float_as_uint(x);
    u = (u + 0x7fffu + ((u >> 16) & 1u)) >> 16;   // RNE, inputs always finite
    return (unsigned short)u;
}
__device__ __forceinline__ float bf2f(unsigned short u) {
    return __uint_as_float(((unsigned int)u) << 16);
}
__device__ __forceinline__ void glds16(const void* g, void* l) {
    __builtin_amdgcn_global_load_lds(
        (const __attribute__((address_space(1))) unsigned int*)g,
        (__attribute__((address_space(3))) unsigned int*)l, 16, 0, 0);
}
// tanh(x) = 1 - 2/(e^{2x}+1); v_exp_f32+v_rcp_f32, ~5 VALU insts.
__device__ __forceinline__ float tanh_fast(float x) {
    float e = __expf(x * 2.0f);
    return fmaf(-2.0f, __builtin_amdgcn_rcpf(e + 1.0f), 1.0f);
}

// Fused prep kernel: block-range dispatch of 5 independent phases.
#define PREP_DEC0   0
#define PREP_CONV0  1024
#define PREP_WT0    8704
#define PREP_PAD0   13312
#define PREP_ENC0   20404
#define PREP_TOTAL  44404

__global__ __launch_bounds__(256) void k_prep(
    const float* __restrict__ enc, const int* __restrict__ xl,
    const float* __restrict__ dec_out, const float* __restrict__ aw_step,
    const float* __restrict__ w_enc, const float* __restrict__ b_enc,
    const float* __restrict__ w_dec, const float* __restrict__ w_conv,
    const float* __restrict__ conv_k,
    unsigned short* __restrict__ Whi, unsigned short* __restrict__ Wlo,
    unsigned short* __restrict__ Ahi, unsigned short* __restrict__ Alo,
    float* __restrict__ dec_a) {
    __shared__ float sbuf[456 + KCONV];
    const int bid = blockIdx.x;
    const int tid = threadIdx.x;

    if (bid < PREP_CONV0) {
        // ---- dec: dec_a[b][n] = b_enc[n] + sum_d dec[b][d]*w_dec[h][d][a] ----
        const int b  = bid >> 5;
        const int n0 = (bid & 31) * 64;
        const int n  = n0 + (tid & 63);
        const int dg = tid >> 6;                   // 0..3, 128 d each
        const int h  = n >> 9, a = n & 511;
        const float* dp = dec_out + (size_t)b * 512 + dg * 128;
        const float* wp = w_dec + ((size_t)h * 512 + dg * 128) * 512 + a;
        float acc = 0.f;
#pragma unroll 8
        for (int d = 0; d < 128; ++d) acc += dp[d] * wp[(size_t)d * 512];
        sbuf[tid] = acc;
        __syncthreads();
        if (tid < 64) {
            float tot = sbuf[tid] + sbuf[tid + 64] + sbuf[tid + 128] + sbuf[tid + 192];
            dec_a[(size_t)b * NN + n0 + tid] = b_enc[n0 + tid] + tot;
        }
    } else if (bid < PREP_WT0) {
        // ---- conv: grouped 1D conv over aw_step -> A cols [512,552) ----
        int r = bid - PREP_CONV0;                  // 7680 = 6*40*32
        const int tch = r % 6;
        const int hc  = (r / 6) % 40;
        const int b   = r / 240;
        const int h   = hc / 10;
        const int t0  = tch * 256;
        float* sAw = sbuf;
        float* sK  = sbuf + 456;
        for (int i = tid; i < 456; i += 256) {
            int ts = t0 - 100 + i;
            sAw[i] = (ts >= 0 && ts < TT) ? aw_step[((size_t)b * TT + ts) * HH + h] : 0.f;
        }
        if (tid < KCONV) sK[tid] = conv_k[(size_t)hc * KCONV + tid];
        __syncthreads();
        int t = t0 + tid;
        if (t < TT) {
            float acc = 0.f;
            for (int k = 0; k < KCONV; ++k) acc += sAw[tid + k] * sK[k];
            size_t o = ((size_t)b * TP + t) * KAUG + 512 + hc;
            unsigned short hi = f2bf(acc);
            Ahi[o] = hi; Alo[o] = f2bf(acc - bf2f(hi));
        }
    } else if (bid < PREP_PAD0) {
        // ---- wt: W planes [N=2048][KAUG], hi/lo ----
        int idx = (bid - PREP_WT0) * 256 + tid;    // 1,179,648
        int n = idx / KAUG, k = idx % KAUG;
        int h = n >> 9, a = n & 511;
        float val = 0.f;
        if (k < 512) {
            val = w_enc[((size_t)h * 512 + k) * 512 + a];
        } else if (k < 552) {
            int j = k - 512; int h2 = j / 10, c = j % 10;
            if (h2 == h) val = w_conv[((size_t)h * 10 + c) * 512 + a];
        }
        unsigned short hi = f2bf(val);
        Whi[idx] = hi;
        Wlo[idx] = f2bf(val - bf2f(hi));
    } else if (bid < PREP_ENC0) {
        // ---- pad: zero rows >=1500 (all cols) + cols [552,576) (rows <1500) ----
        int idx = (bid - PREP_PAD0) * 256 + tid;
        const int tot1 = BB * 36 * KAUG;           // 663552
        const int tot2 = BB * TT * 24;             // 1152000
        size_t o;
        if (idx < tot1) {
            int b = idx / (36 * KAUG); int r2 = idx % (36 * KAUG);
            int t = 1500 + r2 / KAUG;  int k = r2 % KAUG;
            o = ((size_t)b * TP + t) * KAUG + k;
        } else if (idx < tot1 + tot2) {
            int j = idx - tot1;
            int b = j / (TT * 24); int r2 = j % (TT * 24);
            int t = r2 / 24;       int k = 552 + r2 % 24;
            o = ((size_t)b * TP + t) * KAUG + k;
        } else return;
        Ahi[o] = 0; Alo[o] = 0;
    } else {
        // ---- enc: f32 -> A planes cols [0,512); Alo only for 3-product tiles ----
        long idx = (long)(bid - PREP_ENC0) * 256 + tid;   // 6,144,000 float4s
        if (idx >= 6144000L) return;
        long f = idx * 4;
        int b = (int)(f / 768000);
        int r2 = (int)(f % 768000);
        int t = r2 >> 9, e = r2 & 511;
        float4 vv = *reinterpret_cast<const float4*>(enc + f);
        ushort4 h4;
        h4.x = f2bf(vv.x); h4.y = f2bf(vv.y); h4.z = f2bf(vv.z); h4.w = f2bf(vv.w);
        size_t o = ((size_t)b * TP + t) * KAUG + e;
        *reinterpret_cast<ushort4*>(Ahi + o) = h4;
        if (((t & ~127) + 128) > xl[b]) {          // tile containing t runs 3-product
            ushort4 l4;
            l4.x = f2bf(vv.x - bf2f(h4.x));
            l4.y = f2bf(vv.y - bf2f(h4.y));
            l4.z = f2bf(vv.z - bf2f(h4.z));
            l4.w = f2bf(vv.w - bf2f(h4.w));
            *reinterpret_cast<ushort4*>(Alo + o) = l4;
        }
    }
}

// ---------- unified GEMM: 3-product folded into K; 3-buffer counted-vmcnt pipeline ----
// Ah*Bh + Ah*Bl + Al*Bh  ==  one GEMM over 54 K-steps whose per-step plane pointers
// cycle (Ahi/Whi x18, Ahi/Wlo x18, Alo/Whi x18). Valid tiles (m0+128 <= xlen) stop at
// nk=18 (hi*hi only). Every tile uses the same 2-plane layout: 16 KB/buffer -> 3
// buffers = 48 KB LDS -> 3 blocks/CU, vs round-1's 64 KB / 2 blocks.
// Pipeline (T3+T4): stage(t) issued 2 iterations before compute(t); per-iteration wait
// is s_waitcnt vmcnt(4) -- the NEXT tile's 4 loads stay in flight across the barrier
// (never drain to 0 in the loop; m218's counted-vmcnt lever). Single barrier per step:
// buffer (t+2)%3 was last read at compute(t-1), which every wave finished before this
// barrier; stage is issued after it.
// LDS swizzle (both-sides, rule #21): global source pre-swizzled via ko, ds_read via fo.
// XCD map: group g=(b,mtile) -> XCD g%8; each XCD sweeps 16 ntiles of one group
// consecutively (A-panel stays in its L2); adjacent mtiles of the same b land on
// different XCDs, spreading the heavy nk=54 groups.
__global__ __launch_bounds__(256, 3) void k_gemm(
    const unsigned short* __restrict__ Ahi, const unsigned short* __restrict__ Alo,
    const unsigned short* __restrict__ Whi, const unsigned short* __restrict__ Wlo,
    const float* __restrict__ dec_a, const float* __restrict__ vvec,
    const int* __restrict__ xl, float* __restrict__ energy) {
    __shared__ unsigned short lsA[3][4096];   // [buf][128 rows x 32 cols]
    __shared__ unsigned short lsB[3][4096];
    const int bid = blockIdx.x;                       // 6144 = 48*128
    const int g = ((bid >> 7) << 3) + (bid & 7);      // group 0..383 = b*12+mtile
    const int ntile = (bid >> 3) & 15;
    const int b = g / 12, mtile = g % 12;
    const int m0 = mtile * 128, n0 = ntile * 128;
    const int xlen = xl[b];
    const int nk = (m0 + 128 <= xlen) ? 18 : 54;

    const int tid = threadIdx.x;
    const int lane = tid & 63, wave = tid >> 6;
    const int wm = wave >> 1, wn = wave & 1;

    f32x4 acc[4][4];
#pragma unroll
    for (int i = 0; i < 4; i++)
#pragma unroll
        for (int j = 0; j < 4; j++) acc[i][j] = (f32x4){0.f, 0.f, 0.f, 0.f};

    const int row = tid >> 2;
    const int ko  = ((tid & 3) ^ ((tid >> 3) & 3)) * 8;  // pre-swizzled global source
    const size_t abase = ((size_t)b * TP + m0 + row) * KAUG + ko;
    const size_t bbase = ((size_t)n0 + row) * KAUG + ko;
    const int l1 = tid * 8;                              // linear LDS dest (required)
    const int l2 = l1 + 2048;
    const int ar = wm * 64, br = wn * 64;
    const int fo = (lane & 15) * 32 + (((lane >> 4) ^ ((lane >> 1) & 3)) * 8);

    auto stage = [&](int t, int buf) {
        const int seg = (t >= 36) ? 2 : ((t >= 18) ? 1 : 0);   // scalar
        const int k0 = (t - seg * 18) * 32;
        const unsigned short* Ap = (seg == 2) ? Alo : Ahi;
        const unsigned short* Bp = (seg == 1) ? Wlo : Whi;
        glds16(Ap + abase + k0,                     &lsA[buf][l1]);
        glds16(Ap + abase + k0 + (size_t)64 * KAUG, &lsA[buf][l2]);
        glds16(Bp + bbase + k0,                     &lsB[buf][l1]);
        glds16(Bp + bbase + k0 + (size_t)64 * KAUG, &lsB[buf][l2]);
    };
    auto compute = [&](int buf) {
        bf16x8 ah[4], bh[4];
#pragma unroll
        for (int i = 0; i < 4; i++) {
            ah[i] = *(const bf16x8*)&lsA[buf][(ar + i * 16) * 32 + fo];
            bh[i] = *(const bf16x8*)&lsB[buf][(br + i * 16) * 32 + fo];
        }
        __builtin_amdgcn_s_setprio(1);
#pragma unroll
        for (int i = 0; i < 4; i++)
#pragma unroll
            for (int j = 0; j < 4; j++)
                acc[i][j] = __builtin_amdgcn_mfma_f32_16x16x32_bf16(ah[i], bh[j], acc[i][j], 0, 0, 0);
        __builtin_amdgcn_s_setprio(0);
    };

    stage(0, 0);                 // 4 loads
    stage(1, 1);                 // 8 outstanding
    int bc = 0, bp = 2;          // bc = t%3, bp = (t+2)%3
    for (int t = 0; t < nk - 1; ++t) {
        asm volatile("s_waitcnt vmcnt(4)" ::: "memory");  // stage(t) landed; stage(t+1) in flight
        __builtin_amdgcn_s_barrier();
        __builtin_amdgcn_sched_barrier(0);
        if (t + 2 < nk) stage(t + 2, bp);
        __builtin_amdgcn_sched_barrier(0);                // issue loads before ds_read burst
        compute(bc);
        __builtin_amdgcn_sched_barrier(0);
        bc = (bc == 2) ? 0 : bc + 1;
        bp = (bp == 2) ? 0 : bp + 1;
    }
    asm volatile("s_waitcnt vmcnt(0)" ::: "memory");      // only stage(nk-1) left
    __builtin_amdgcn_s_barrier();
    __builtin_amdgcn_sched_barrier(0);
    compute(bc);

    // Epilogue: x = acc + dec_a[b][n]; energy += tanh(x)*v[n], reduced over head's A-dim
    const int h = ntile >> 2;            // 128-wide tile lies inside one head
    const int kg = lane >> 4;
    float dv[4], vv[4];
#pragma unroll
    for (int j = 0; j < 4; j++) {
        int ng = n0 + wn * 64 + j * 16 + (lane & 15);
        dv[j] = dec_a[(size_t)b * NN + ng];
        vv[j] = vvec[ng];
    }
#pragma unroll
    for (int i = 0; i < 4; i++) {
        float part[4] = {0.f, 0.f, 0.f, 0.f};
#pragma unroll
        for (int j = 0; j < 4; j++)
#pragma unroll
            for (int r = 0; r < 4; r++)
                part[r] += tanh_fast(acc[i][j][r] + dv[j]) * vv[j];
#pragma unroll
        for (int r = 0; r < 4; r++) {
            float s = part[r];
            s += __shfl_xor(s, 1, 64);
            s += __shfl_xor(s, 2, 64);
            s += __shfl_xor(s, 4, 64);
            s += __shfl_xor(s, 8, 64);
            if ((lane & 15) == 0) {
                int t = m0 + wm * 64 + i * 16 + kg * 4 + r;
                if (t < TT)
                    atomicAdd(&energy[((size_t)b * HH + h) * TP + t], s);
            }
        }
    }
}

// ---------- masked softmax over time (replicates energy * (+1 / -1024) mask) ----------
__global__ __launch_bounds__(512) void k_softmax(const float* __restrict__ energy,
                                                 const int* __restrict__ x_lens,
                                                 float* __restrict__ aw) {
    const int b = blockIdx.x >> 2, h = blockIdx.x & 3;
    const int tid = threadIdx.x;
    __shared__ float sE[TT];
    __shared__ float red[512];
    const int xlen = x_lens[b];
    float lmax = -3.4e38f;
    for (int t = tid; t < TT; t += 512) {
        float e = energy[((size_t)b * HH + h) * TP + t];
        float m = (t < xlen) ? e : e * -1024.0f;
        sE[t] = m;
        lmax = fmaxf(lmax, m);
    }
    red[tid] = lmax; __syncthreads();
    for (int s = 256; s > 0; s >>= 1) { if (tid < s) red[tid] = fmaxf(red[tid], red[tid + s]); __syncthreads(); }
    float mx = red[0]; __syncthreads();
    float lsum = 0.f;
    for (int t = tid; t < TT; t += 512) {
        float ex = expf(sE[t] - mx);
        sE[t] = ex; lsum += ex;
    }
    red[tid] = lsum; __syncthreads();
    for (int s = 256; s > 0; s >>= 1) { if (tid < s) red[tid] += red[tid + s]; __syncthreads(); }
    float sum = red[0];
    for (int t = tid; t < TT; t += 512)
        aw[((size_t)b * TT + t) * HH + h] = sE[t] / sum;
}

// ---------- ctx_h[b][h][e] = sum_t aw[b][t][h] * enc[b][t][e] ----------
// chunk=64: 24x32=768 blocks (~3/CU) for latency hiding, vs 384 at chunk=128.
__global__ __launch_bounds__(512) void k_ctx(const float* __restrict__ enc,
                                             const float* __restrict__ aw,
                                             float* __restrict__ ctx_h) {
    const int chunk = blockIdx.x, b = blockIdx.y;
    const int t0 = chunk * 64;
    const int nt = (TT - t0 < 64) ? (TT - t0) : 64;
    __shared__ float sA[64 * 4];
    const int tid = threadIdx.x;
    for (int i = tid; i < nt * 4; i += 512)
        sA[i] = aw[((size_t)b * TT + t0) * HH + i];
    __syncthreads();
    float a0 = 0.f, a1 = 0.f, a2 = 0.f, a3 = 0.f;
    const float* ep = enc + ((size_t)b * TT + t0) * EE + tid;
    if (nt == 64) {
#pragma unroll 8
        for (int tt = 0; tt < 64; ++tt) {
            float ev = ep[(size_t)tt * EE];
            a0 += sA[tt * 4 + 0] * ev; a1 += sA[tt * 4 + 1] * ev;
            a2 += sA[tt * 4 + 2] * ev; a3 += sA[tt * 4 + 3] * ev;
        }
    } else {
        for (int tt = 0; tt < nt; ++tt) {
            float ev = ep[(size_t)tt * EE];
            a0 += sA[tt * 4 + 0] * ev; a1 += sA[tt * 4 + 1] * ev;
            a2 += sA[tt * 4 + 2] * ev; a3 += sA[tt * 4 + 3] * ev;
        }
    }
    atomicAdd(&ctx_h[((size_t)b * HH + 0) * EE + tid], a0);
    atomicAdd(&ctx_h[((size_t)b * HH + 1) * EE + tid], a1);
    atomicAdd(&ctx_h[((size_t)b * HH + 2) * EE + tid], a2);
    atomicAdd(&ctx_h[((size_t)b * HH + 3) * EE + tid], a3);
}

// ---------- ctx = ctx_h @ w_mha + b_mha ----------
__global__ __launch_bounds__(256) void k_mha(const float* __restrict__ ctx_h,
                                             const float* __restrict__ w_mha,
                                             const float* __restrict__ b_mha,
                                             float* __restrict__ out) {
    __shared__ float sred[256];
    const int tid = threadIdx.x;
    const int b  = blockIdx.x >> 2;
    const int eo = ((blockIdx.x & 3) << 7) + (tid & 127);
    const int kg = tid >> 7;                   // 0..1, 1024 k each
    const float* c = ctx_h + (size_t)b * NN + kg * 1024;
    const float* w = w_mha + ((size_t)kg * 1024) * EE + eo;
    float acc = 0.f;
#pragma unroll 8
    for (int k = 0; k < 1024; ++k) acc += c[k] * w[(size_t)k * EE];
    sred[tid] = acc;
    __syncthreads();
    if (tid < 128)
        out[(size_t)b * EE + eo] = b_mha[eo] + sred[tid] + sred[tid + 128];
}

extern "C" void kernel_launch(void* const* d_in, const int* in_sizes, int n_in,
                              void* d_out, int out_size, void* d_ws, size_t ws_size,
                              hipStream_t stream) {
    (void)in_sizes; (void)n_in; (void)out_size;
    const float* enc    = (const float*)d_in[0];
    const int*   xlen   = (const int*)d_in[1];
    const float* dec    = (const float*)d_in[2];
    const float* aw_in  = (const float*)d_in[3];
    const float* w_enc  = (const float*)d_in[4];
    const float* b_enc  = (const float*)d_in[5];
    const float* w_dec  = (const float*)d_in[6];
    const float* w_conv = (const float*)d_in[7];
    const float* convk  = (const float*)d_in[8];
    const float* v      = (const float*)d_in[9];
    const float* w_mha  = (const float*)d_in[10];
    const float* b_mha  = (const float*)d_in[11];
    float* out = (float*)d_out;

    // ws layout (needs ~119.3 MB)
    char* ws = (char*)d_ws;
    unsigned short* Whi = (unsigned short*)ws;                          // 2,359,296 B
    unsigned short* Wlo = Whi + (size_t)NN * KAUG;                      // 2,359,296 B
    unsigned short* Ahi = (unsigned short*)(ws + 4718592);              // 56,623,104 B
    unsigned short* Alo = Ahi + (size_t)BB * TP * KAUG;                 // 56,623,104 B
    float* dec_a  = (float*)(ws + 117964800);                           //   262,144 B
    float* energy = (float*)(ws + 118226944);                           //   786,432 B
    float* ctx_h  = (float*)(ws + 119013376);                           //   262,144 B
    (void)ws_size;

    hipMemsetAsync(energy, 0, 786432 + 262144, stream);  // energy + ctx_h (contiguous)

    k_prep<<<dim3(PREP_TOTAL), 256, 0, stream>>>(enc, xlen, dec, aw_in, w_enc, b_enc,
                                                 w_dec, w_conv, convk,
                                                 Whi, Wlo, Ahi, Alo, dec_a);
    k_gemm<<<dim3(6144), 256, 0, stream>>>(Ahi, Alo, Whi, Wlo, dec_a, v, xlen, energy);
    k_softmax<<<dim3(BB * HH), 512, 0, stream>>>(energy, xlen, out + 16384);
    k_ctx <<<dim3(24, BB), 512, 0, stream>>>(enc, out + 16384, ctx_h);
    k_mha <<<dim3(128), 256, 0, stream>>>(ctx_h, w_mha, b_mha, out);
}